// Round 24
// baseline (104.957 us; speedup 1.0000x reference)
//
#include <hip/hip_runtime.h>
#include <math.h>

#define B 4
#define C 64
#define H 256
#define W 256
#define HW (H*W)            // 65536
#define CHW (C*HW)          // 4194304
#define BCHW (B*CHW)        // 16777216

typedef _Float16 half8v __attribute__((ext_vector_type(8)));
typedef float f32x4 __attribute__((ext_vector_type(4)));

// ws layout: 3 ushort(f16) planes of BCHW each (100 MB): q, k, v

__device__ inline ushort f16_bits(float f) {
    _Float16 h = (_Float16)f;
    return *(ushort*)&h;
}

// raw barrier: drain LDS only; global loads/stores stay in flight
#define LDS_BARRIER() do { \
    asm volatile("s_waitcnt lgkmcnt(0)" ::: "memory"); \
    __builtin_amdgcn_s_barrier(); \
} while (0)

// ---------------------------------------------------------------------------
// K1: qkv 1x1 conv as f16 MFMA GEMM. 6 chunks x 32 oc. WAVE-PRIVATE repack:
// zero block barriers; launch_bounds(256,4) -> 64 VGPR, no spill.
// (unchanged from r23)
// ---------------------------------------------------------------------------
#define QPAD 72   // wave tile row stride (ushorts); 144 B, 16B-aligned

__global__ __launch_bounds__(256, 4) void qkv_kernel(
    const float* __restrict__ x, const float* __restrict__ w,
    const float* __restrict__ bias, ushort* __restrict__ qkv)
{
    __shared__ ushort tile[4][32 * QPAD];  // 18.4 KB
    int t = threadIdx.x;
    int lane = t & 63, wv = t >> 6;
    int l15 = lane & 15, l4 = lane >> 4;
    int p0 = blockIdx.x * 256;
    int b = p0 >> 16;
    int ppx = p0 & (HW - 1);               // pixel offset WITHIN batch b
    int pxw = ppx + wv * 64;

    const float* xb = x + (size_t)b * CHW;
    ushort* wt = tile[wv];                 // wave-private repack tile

    half8v bfr[4][2];
    #pragma unroll
    for (int pf = 0; pf < 4; ++pf)
        #pragma unroll
        for (int kc = 0; kc < 2; ++kc) {
            int k0 = kc * 32 + l4 * 8;
            int px = pxw + pf * 16 + l15;
            half8v hv;
            #pragma unroll
            for (int j = 0; j < 8; ++j)
                hv[j] = (_Float16)xb[(size_t)(k0 + j) * HW + px];
            bfr[pf][kc] = hv;
        }

    auto load_afr = [&](int ocb, half8v afr[2][2]) {
        #pragma unroll
        for (int nf = 0; nf < 2; ++nf)
            #pragma unroll
            for (int kc = 0; kc < 2; ++kc) {
                int oc = ocb + nf * 16 + l15;
                int k0 = kc * 32 + l4 * 8;
                const float4* wp = (const float4*)&w[oc * 64 + k0];
                float4 wa = wp[0], wb2 = wp[1];
                half8v a;
                a[0] = (_Float16)wa.x;  a[1] = (_Float16)wa.y;
                a[2] = (_Float16)wa.z;  a[3] = (_Float16)wa.w;
                a[4] = (_Float16)wb2.x; a[5] = (_Float16)wb2.y;
                a[6] = (_Float16)wb2.z; a[7] = (_Float16)wb2.w;
                afr[nf][kc] = a;
            }
    };

    half8v afrA[2][2], afrB[2][2];
    load_afr(0, afrA);

    #pragma unroll
    for (int ch = 0; ch < 6; ++ch) {
        int ocb = ch * 32;
        half8v (*cur)[2] = (ch & 1) ? afrB : afrA;
        half8v (*nxt)[2] = (ch & 1) ? afrA : afrB;

        f32x4 acc[2][4];
        #pragma unroll
        for (int nf = 0; nf < 2; ++nf)
            #pragma unroll
            for (int pf = 0; pf < 4; ++pf) acc[nf][pf] = (f32x4)0.f;

        #pragma unroll
        for (int kc = 0; kc < 2; ++kc)
            #pragma unroll
            for (int nf = 0; nf < 2; ++nf)
                #pragma unroll
                for (int pf = 0; pf < 4; ++pf)
                    acc[nf][pf] = __builtin_amdgcn_mfma_f32_16x16x32_f16(
                        cur[nf][kc], bfr[pf][kc], acc[nf][pf], 0, 0, 0);

        if (ch < 5) load_afr(ocb + 32, nxt);

        #pragma unroll
        for (int nf = 0; nf < 2; ++nf)
            #pragma unroll
            for (int r = 0; r < 4; ++r) {
                int ocl = nf * 16 + l4 * 4 + r;
                float bv = bias[ocb + ocl];
                #pragma unroll
                for (int pf = 0; pf < 4; ++pf)
                    wt[ocl * QPAD + pf * 16 + l15] =
                        f16_bits(acc[nf][pf][r] + bv);
            }

        asm volatile("s_waitcnt lgkmcnt(0)" ::: "memory");

        #pragma unroll
        for (int p = 0; p < 4; ++p) {
            int row = p * 8 + (lane >> 3);
            int c8  = lane & 7;
            uint4 val = *(const uint4*)&wt[row * QPAD + c8 * 8];
            int oc = ocb + row;
            ushort* dst = qkv + (size_t)(oc >> 6) * BCHW
                        + ((size_t)b * 64 + (oc & 63)) * HW + pxw + c8 * 8;
            *(uint4*)dst = val;
        }
    }
}

// ---------------------------------------------------------------------------
// K2 (fused): 2 blocks per bc (grid 512), 4 h-tiles each -> 2 blocks/CU.
// Same r21/r23 tile pipeline (T14 Q-stage split, vector conv/softmax,
// 6 LDS-only barriers/tile). XCD swizzle co-locates each bc's pair.
// ---------------------------------------------------------------------------
#define SST 268                   // sbuf stride for S rows (f32); 268*4%16==0
#define ATS 264                   // attn row stride (f16)
#define SOT 264                   // out-repack stride (f32)
#define VSTR 268                  // V staging stride (f16)

__global__ __launch_bounds__(512, 2) void fused_kernel(
    const ushort* __restrict__ qf, const ushort* __restrict__ kf,
    const ushort* __restrict__ vf,
    const float* __restrict__ wdw, const float* __restrict__ bdw,
    const float* __restrict__ x, float* __restrict__ out)
{
    __shared__ float sbuf[34 * SST];        // 35.6 KB (V-stage / S / attn / out)
    __shared__ ushort qlds[48 * 256];       // 24 KB, XOR-swizzled Q tile

    int t = threadIdx.x;
    int lane = t & 63, wv = t >> 6;         // 8 waves
    int l15 = lane & 15, l4 = lane >> 4;
    int col4 = t & 63, rg = t >> 6;         // conv layout: 64 col-groups x 8 row-groups
    int c0 = col4 * 4;

    int bid = blockIdx.x;
    int swz = (bid & 7) * 64 + (bid >> 3);  // bc's 2 halves -> same XCD
    int bc = swz >> 1;
    int tb = (swz & 1) * 4;                 // 4 h-tiles per block
    int c = bc & 63;

    const ushort* qb = qf + (size_t)bc * HW;
    const ushort* kb = kf + (size_t)bc * HW;
    const ushort* vb = vf + (size_t)bc * HW;
    const float*  xb = x  + (size_t)bc * HW;
    float*        ob = out + (size_t)bc * HW;

    int g0 = wv * 32;

    // ---- preload K fragments (16B row gathers, once per block) ----
    half8v ka[2][8];
    {
        const ushort* kr0 = kb + (g0 + l15) * 256 + l4 * 8;
        const ushort* kr1 = kb + (g0 + 16 + l15) * 256 + l4 * 8;
        #pragma unroll
        for (int kc = 0; kc < 8; ++kc) {
            ka[0][kc] = *(const half8v*)(kr0 + kc * 32);
            ka[1][kc] = *(const half8v*)(kr1 + kc * 32);
        }
    }

    // ---- preload V^T fragments via LDS transpose (fully unrolled) ----
    half8v va[2][8];
    {
        ushort* vstage = (ushort*)sbuf;     // [64][VSTR] = 34.3 KB
        #pragma unroll
        for (int hc = 0; hc < 4; ++hc) {
            #pragma unroll
            for (int s = 0; s < 4; ++s) {
                int id = t + s * 512;       // 64 rows x 32 segs
                int row = id >> 5, seg = id & 31;
                *(uint4*)&vstage[row * VSTR + seg * 8] =
                    *(const uint4*)(vb + (hc * 64 + row) * 256 + seg * 8);
            }
            LDS_BARRIER();
            #pragma unroll
            for (int gf = 0; gf < 2; ++gf)
                #pragma unroll
                for (int kcl = 0; kcl < 2; ++kcl) {
                    half8v v;
                    #pragma unroll
                    for (int j = 0; j < 8; ++j)
                        v[j] = *(const _Float16*)&vstage[(kcl * 32 + l4 * 8 + j) * VSTR
                                                         + g0 + gf * 16 + l15];
                    va[gf][hc * 2 + kcl] = v;
                }
            LDS_BARRIER();
        }
    }

    float w00 = wdw[c*9+0], w01 = wdw[c*9+1], w02 = wdw[c*9+2];
    float w10 = wdw[c*9+3], w11 = wdw[c*9+4], w12 = wdw[c*9+5];
    float w20 = wdw[c*9+6], w21 = wdw[c*9+7], w22 = wdw[c*9+8];
    float bias = bdw[c];

    half8v ones;
    #pragma unroll
    for (int j = 0; j < 8; ++j) ones[j] = (_Float16)1.0f;

    // ---- Q-stage addressing (per-thread constants) + first-tile prologue ----
    int srow[3], scch[3];
    #pragma unroll
    for (int s = 0; s < 3; ++s) {
        int id = t + s * 512;               // 0..1535: 48 rows x 32 segs
        srow[s] = id >> 5; scch[s] = id & 31;
    }
    uint4 sv0, sv1, sv2;
    {
        int b0 = tb * 32;
        int hq0 = min(max(b0 - 1 + srow[0], 0), 255);
        int hq1 = min(max(b0 - 1 + srow[1], 0), 255);
        int hq2 = min(max(b0 - 1 + srow[2], 0), 255);
        sv0 = *(const uint4*)(qb + hq0 * 256 + scch[0] * 8);
        sv1 = *(const uint4*)(qb + hq1 * 256 + scch[1] * 8);
        sv2 = *(const uint4*)(qb + hq2 * 256 + scch[2] * 8);
        *(uint4*)((char*)qlds + srow[0] * 512 + ((scch[0] ^ (srow[0] & 7)) << 4)) = sv0;
        *(uint4*)((char*)qlds + srow[1] * 512 + ((scch[1] ^ (srow[1] & 7)) << 4)) = sv1;
        *(uint4*)((char*)qlds + srow[2] * 512 + ((scch[2] ^ (srow[2] & 7)) << 4)) = sv2;
    }

    #pragma unroll 1
    for (int tile = 0; tile < 4; ++tile) {
        int h0 = (tb + tile) * 32;

        LDS_BARRIER();   // BAR_A: qlds(t) visible; prev out-pass sbuf reads done

        // ===== Phase 1: S = Q K^T (Q from swizzled LDS, K from regs) =======
        {
            f32x4 acc[3][2];
            #pragma unroll
            for (int i = 0; i < 3; ++i)
                #pragma unroll
                for (int j = 0; j < 2; ++j) acc[i][j] = (f32x4)0.f;

            #pragma unroll
            for (int kc = 0; kc < 8; ++kc) {
                int ch4 = kc * 4 + l4;
                half8v q0 = *(const half8v*)((char*)qlds + (l15)      * 512 + ((ch4 ^ ( l15       & 7)) << 4));
                half8v q1 = *(const half8v*)((char*)qlds + (16 + l15) * 512 + ((ch4 ^ ((16 + l15) & 7)) << 4));
                half8v q2 = *(const half8v*)((char*)qlds + (32 + l15) * 512 + ((ch4 ^ ((32 + l15) & 7)) << 4));
                __builtin_amdgcn_s_setprio(1);
                acc[0][0] = __builtin_amdgcn_mfma_f32_16x16x32_f16(q0, ka[0][kc], acc[0][0], 0, 0, 0);
                acc[0][1] = __builtin_amdgcn_mfma_f32_16x16x32_f16(q0, ka[1][kc], acc[0][1], 0, 0, 0);
                acc[1][0] = __builtin_amdgcn_mfma_f32_16x16x32_f16(q1, ka[0][kc], acc[1][0], 0, 0, 0);
                acc[1][1] = __builtin_amdgcn_mfma_f32_16x16x32_f16(q1, ka[1][kc], acc[1][1], 0, 0, 0);
                acc[2][0] = __builtin_amdgcn_mfma_f32_16x16x32_f16(q2, ka[0][kc], acc[2][0], 0, 0, 0);
                acc[2][1] = __builtin_amdgcn_mfma_f32_16x16x32_f16(q2, ka[1][kc], acc[2][1], 0, 0, 0);
                __builtin_amdgcn_s_setprio(0);
            }

            // ---- issue next tile's Q loads (hide HBM latency under S-store+conv)
            if (tile < 3) {
                int nh0 = h0 + 32;
                int hq0 = min(max(nh0 - 1 + srow[0], 0), 255);
                int hq1 = min(max(nh0 - 1 + srow[1], 0), 255);
                int hq2 = min(max(nh0 - 1 + srow[2], 0), 255);
                sv0 = *(const uint4*)(qb + hq0 * 256 + scch[0] * 8);
                sv1 = *(const uint4*)(qb + hq1 * 256 + scch[1] * 8);
                sv2 = *(const uint4*)(qb + hq2 * 256 + scch[2] * 8);
            }

            // ---- S store ----
            #pragma unroll
            for (int hf = 0; hf < 3; ++hf)
                #pragma unroll
                for (int gf = 0; gf < 2; ++gf)
                    #pragma unroll
                    for (int r = 0; r < 4; ++r) {
                        int cr = hf * 16 + l4 * 4 + r;
                        if (cr < 34)
                            sbuf[cr * SST + g0 + gf * 16 + l15] = acc[hf][gf][r];
                    }
        }
        LDS_BARRIER();   // BAR_B: S visible; all P1 qlds reads done

        // ---- stage next tile's Q into qlds (writes drain at BAR_C) ----
        if (tile < 3) {
            *(uint4*)((char*)qlds + srow[0] * 512 + ((scch[0] ^ (srow[0] & 7)) << 4)) = sv0;
            *(uint4*)((char*)qlds + srow[1] * 512 + ((scch[1] ^ (srow[1] & 7)) << 4)) = sv1;
            *(uint4*)((char*)qlds + srow[2] * 512 + ((scch[2] ^ (srow[2] & 7)) << 4)) = sv2;
        }

        // ===== Phase 2: conv3x3, 4 cols/thread (b128 + shfl boundaries) =====
        float y[4][4], rmax[4];
        {
            f32x4 m0v, m1v, m2v;
            float l0v, r0v, l1v, r1v, l2v, r2v;

            auto rdrow = [&](int k, f32x4 &mv, float &lv, float &rv) {
                int sr = rg * 4 + k;
                bool valid = !((h0 == 0 && sr == 0) || (h0 + sr > 256));
                f32x4 z = (f32x4)0.f;
                mv = valid ? *(const f32x4*)&sbuf[sr * SST + c0] : z;
                float le = __shfl_up(mv[3], 1);
                float re = __shfl_down(mv[0], 1);
                lv = (col4 == 0) ? 0.f : le;
                rv = (col4 == 63) ? 0.f : re;
            };

            rdrow(0, m0v, l0v, r0v);
            rdrow(1, m1v, l1v, r1v);
            #pragma unroll
            for (int k = 2; k < 6; ++k) {
                rdrow(k, m2v, l2v, r2v);
                int i = k - 2;
                #pragma unroll
                for (int j = 0; j < 4; ++j) {
                    float a0 = (j == 0) ? l0v : m0v[j-1];
                    float b0 = m0v[j];
                    float e0 = (j == 3) ? r0v : m0v[j+1];
                    float a1 = (j == 0) ? l1v : m1v[j-1];
                    float b1 = m1v[j];
                    float e1 = (j == 3) ? r1v : m1v[j+1];
                    float a2 = (j == 0) ? l2v : m2v[j-1];
                    float b2 = m2v[j];
                    float e2 = (j == 3) ? r2v : m2v[j+1];
                    y[i][j] = bias
                        + w00*a0 + w01*b0 + w02*e0
                        + w10*a1 + w11*b1 + w12*e1
                        + w20*a2 + w21*b2 + w22*e2;
                }
                m0v = m1v; l0v = l1v; r0v = r1v;
                m1v = m2v; l1v = l2v; r1v = r2v;
            }

            #pragma unroll
            for (int i = 0; i < 4; ++i) {
                float m = fmaxf(fmaxf(y[i][0], y[i][1]), fmaxf(y[i][2], y[i][3]));
                #pragma unroll
                for (int off = 32; off > 0; off >>= 1)
                    m = fmaxf(m, __shfl_xor(m, off));
                rmax[i] = m;
            }
        }
        LDS_BARRIER();   // BAR_C: conv reads done; qlds writes drained

        // ===== Phase 3: exp -> f16 attn (b64 stores) =====
        ushort* attnb = (ushort*)sbuf;
        #pragma unroll
        for (int i = 0; i < 4; ++i) {
            int R = rg * 4 + i;
            union { ushort u[4]; uint2 v; } pk;
            #pragma unroll
            for (int j = 0; j < 4; ++j)
                pk.u[j] = f16_bits(__expf(y[i][j] - rmax[i]));
            *(uint2*)&attnb[R * ATS + c0] = pk.v;
        }
        LDS_BARRIER();   // BAR_D: attn visible

        // ===== Phase 4: PV + ones-sum (attn from LDS, V from regs) =====
        f32x4 pacc[2][2], accs[2];
        #pragma unroll
        for (int i = 0; i < 2; ++i) {
            accs[i] = (f32x4)0.f;
            #pragma unroll
            for (int j = 0; j < 2; ++j) pacc[i][j] = (f32x4)0.f;
        }

        #pragma unroll
        for (int kc = 0; kc < 8; ++kc) {
            half8v af0 = *(const half8v*)&attnb[l15 * ATS + kc * 32 + l4 * 8];
            half8v af1 = *(const half8v*)&attnb[(16 + l15) * ATS + kc * 32 + l4 * 8];
            __builtin_amdgcn_s_setprio(1);
            pacc[0][0] = __builtin_amdgcn_mfma_f32_16x16x32_f16(af0, va[0][kc], pacc[0][0], 0, 0, 0);
            pacc[0][1] = __builtin_amdgcn_mfma_f32_16x16x32_f16(af0, va[1][kc], pacc[0][1], 0, 0, 0);
            accs[0]    = __builtin_amdgcn_mfma_f32_16x16x32_f16(af0, ones, accs[0], 0, 0, 0);
            pacc[1][0] = __builtin_amdgcn_mfma_f32_16x16x32_f16(af1, va[0][kc], pacc[1][0], 0, 0, 0);
            pacc[1][1] = __builtin_amdgcn_mfma_f32_16x16x32_f16(af1, va[1][kc], pacc[1][1], 0, 0, 0);
            accs[1]    = __builtin_amdgcn_mfma_f32_16x16x32_f16(af1, ones, accs[1], 0, 0, 0);
            __builtin_amdgcn_s_setprio(0);
        }
        LDS_BARRIER();   // BAR_E: attn reads done before og overlay

        // ===== repack normalized output into LDS =====
        float* og = sbuf;                  // [32][SOT]
        #pragma unroll
        for (int hf = 0; hf < 2; ++hf)
            #pragma unroll
            for (int r = 0; r < 4; ++r) {
                int row = hf * 16 + l4 * 4 + r;
                float inv = 1.0f / accs[hf][r];
                #pragma unroll
                for (int wf = 0; wf < 2; ++wf)
                    og[row * SOT + g0 + wf * 16 + l15] = pacc[hf][wf][r] * inv;
            }
        LDS_BARRIER();   // BAR_F: og visible

        // ===== coalesced out pass: +x residual, 16B stores =====
        #pragma unroll
        for (int s = 0; s < 4; ++s) {
            int id = t + s * 512;          // 0..2047
            int row = id >> 6, seg = id & 63;
            f32x4 v = *(const f32x4*)&og[row * SOT + seg * 4];
            f32x4 xr = *(const f32x4*)&xb[(h0 + row) * 256 + seg * 4];
            v += xr;
            *(f32x4*)&ob[(h0 + row) * 256 + seg * 4] = v;
        }
        // loop-top BAR_A guards og reads vs next S-store and publishes qlds(t+1)
    }
}

// ---------------------------------------------------------------------------
extern "C" void kernel_launch(void* const* d_in, const int* in_sizes, int n_in,
                              void* d_out, int out_size, void* d_ws, size_t ws_size,
                              hipStream_t stream)
{
    const float* x     = (const float*)d_in[0];
    const float* w_qkv = (const float*)d_in[1];
    const float* b_qkv = (const float*)d_in[2];
    const float* w_dw  = (const float*)d_in[3];
    const float* b_dw  = (const float*)d_in[4];

    ushort* qf = (ushort*)d_ws;                  // q plane
    ushort* kf = qf + (size_t)BCHW;              // k plane
    ushort* vf = kf + (size_t)BCHW;              // v plane
    float*  out = (float*)d_out;

    qkv_kernel  <<<B * HW / 256, 256, 0, stream>>>(x, w_qkv, b_qkv, qf);
    fused_kernel<<<B * C * 2,    512, 0, stream>>>(qf, kf, vf, w_dw, b_dw, x, out);
}

// Round 25
// 97.271 us; speedup vs baseline: 1.0790x; 1.0790x over previous
//
#include <hip/hip_runtime.h>
#include <math.h>

#define B 4
#define C 64
#define H 256
#define W 256
#define HW (H*W)            // 65536
#define CHW (C*HW)          // 4194304
#define BCHW (B*CHW)        // 16777216

typedef _Float16 half8v __attribute__((ext_vector_type(8)));
typedef float f32x4 __attribute__((ext_vector_type(4)));

// ws layout: 3 ushort(f16) planes of BCHW each (100 MB): q, k, v

__device__ inline ushort f16_bits(float f) {
    _Float16 h = (_Float16)f;
    return *(ushort*)&h;
}

// raw barrier: drain LDS only; global loads/stores stay in flight
#define LDS_BARRIER() do { \
    asm volatile("s_waitcnt lgkmcnt(0)" ::: "memory"); \
    __builtin_amdgcn_s_barrier(); \
} while (0)

// ---------------------------------------------------------------------------
// K1: qkv 1x1 conv as f16 MFMA GEMM. 6 chunks x 32 oc. WAVE-PRIVATE repack:
// zero block barriers (same-wave DS ordering + lgkmcnt). launch_bounds(256,4)
// -> 64 VGPR, no spill.
// ---------------------------------------------------------------------------
#define QPAD 72   // wave tile row stride (ushorts); 144 B, 16B-aligned

__global__ __launch_bounds__(256, 4) void qkv_kernel(
    const float* __restrict__ x, const float* __restrict__ w,
    const float* __restrict__ bias, ushort* __restrict__ qkv)
{
    __shared__ ushort tile[4][32 * QPAD];  // 18.4 KB
    int t = threadIdx.x;
    int lane = t & 63, wv = t >> 6;
    int l15 = lane & 15, l4 = lane >> 4;
    int p0 = blockIdx.x * 256;
    int b = p0 >> 16;
    int ppx = p0 & (HW - 1);               // pixel offset WITHIN batch b
    int pxw = ppx + wv * 64;

    const float* xb = x + (size_t)b * CHW;
    ushort* wt = tile[wv];                 // wave-private repack tile

    half8v bfr[4][2];
    #pragma unroll
    for (int pf = 0; pf < 4; ++pf)
        #pragma unroll
        for (int kc = 0; kc < 2; ++kc) {
            int k0 = kc * 32 + l4 * 8;
            int px = pxw + pf * 16 + l15;
            half8v hv;
            #pragma unroll
            for (int j = 0; j < 8; ++j)
                hv[j] = (_Float16)xb[(size_t)(k0 + j) * HW + px];
            bfr[pf][kc] = hv;
        }

    auto load_afr = [&](int ocb, half8v afr[2][2]) {
        #pragma unroll
        for (int nf = 0; nf < 2; ++nf)
            #pragma unroll
            for (int kc = 0; kc < 2; ++kc) {
                int oc = ocb + nf * 16 + l15;
                int k0 = kc * 32 + l4 * 8;
                const float4* wp = (const float4*)&w[oc * 64 + k0];
                float4 wa = wp[0], wb2 = wp[1];
                half8v a;
                a[0] = (_Float16)wa.x;  a[1] = (_Float16)wa.y;
                a[2] = (_Float16)wa.z;  a[3] = (_Float16)wa.w;
                a[4] = (_Float16)wb2.x; a[5] = (_Float16)wb2.y;
                a[6] = (_Float16)wb2.z; a[7] = (_Float16)wb2.w;
                afr[nf][kc] = a;
            }
    };

    half8v afrA[2][2], afrB[2][2];
    load_afr(0, afrA);

    #pragma unroll
    for (int ch = 0; ch < 6; ++ch) {
        int ocb = ch * 32;
        half8v (*cur)[2] = (ch & 1) ? afrB : afrA;
        half8v (*nxt)[2] = (ch & 1) ? afrA : afrB;

        f32x4 acc[2][4];
        #pragma unroll
        for (int nf = 0; nf < 2; ++nf)
            #pragma unroll
            for (int pf = 0; pf < 4; ++pf) acc[nf][pf] = (f32x4)0.f;

        #pragma unroll
        for (int kc = 0; kc < 2; ++kc)
            #pragma unroll
            for (int nf = 0; nf < 2; ++nf)
                #pragma unroll
                for (int pf = 0; pf < 4; ++pf)
                    acc[nf][pf] = __builtin_amdgcn_mfma_f32_16x16x32_f16(
                        cur[nf][kc], bfr[pf][kc], acc[nf][pf], 0, 0, 0);

        if (ch < 5) load_afr(ocb + 32, nxt);

        #pragma unroll
        for (int nf = 0; nf < 2; ++nf)
            #pragma unroll
            for (int r = 0; r < 4; ++r) {
                int ocl = nf * 16 + l4 * 4 + r;
                float bv = bias[ocb + ocl];
                #pragma unroll
                for (int pf = 0; pf < 4; ++pf)
                    wt[ocl * QPAD + pf * 16 + l15] =
                        f16_bits(acc[nf][pf][r] + bv);
            }

        asm volatile("s_waitcnt lgkmcnt(0)" ::: "memory");

        #pragma unroll
        for (int p = 0; p < 4; ++p) {
            int row = p * 8 + (lane >> 3);
            int c8  = lane & 7;
            uint4 val = *(const uint4*)&wt[row * QPAD + c8 * 8];
            int oc = ocb + row;
            ushort* dst = qkv + (size_t)(oc >> 6) * BCHW
                        + ((size_t)b * 64 + (oc & 63)) * HW + pxw + c8 * 8;
            *(uint4*)dst = val;
        }
    }
}

// ---------------------------------------------------------------------------
// K2 (fused, persistent per-bc, grid 256, 512 thr): T14 Q-stage split,
// vector conv/softmax, 6 LDS-only barriers/tile. (r23 best configuration)
// ---------------------------------------------------------------------------
#define SST 268                   // sbuf stride for S rows (f32); 268*4%16==0
#define ATS 264                   // attn row stride (f16)
#define SOT 264                   // out-repack stride (f32)
#define VSTR 268                  // V staging stride (f16)

__global__ __launch_bounds__(512, 2) void fused_kernel(
    const ushort* __restrict__ qf, const ushort* __restrict__ kf,
    const ushort* __restrict__ vf,
    const float* __restrict__ wdw, const float* __restrict__ bdw,
    const float* __restrict__ x, float* __restrict__ out)
{
    __shared__ float sbuf[34 * SST];        // 35.6 KB (V-stage / S / attn / out)
    __shared__ ushort qlds[48 * 256];       // 24 KB, XOR-swizzled Q tile

    int t = threadIdx.x;
    int lane = t & 63, wv = t >> 6;         // 8 waves
    int l15 = lane & 15, l4 = lane >> 4;
    int col4 = t & 63, rg = t >> 6;         // conv layout: 64 col-groups x 8 row-groups
    int c0 = col4 * 4;

    int bc = blockIdx.x;                    // one block per (b,c)
    int c = bc & 63;

    const ushort* qb = qf + (size_t)bc * HW;
    const ushort* kb = kf + (size_t)bc * HW;
    const ushort* vb = vf + (size_t)bc * HW;
    const float*  xb = x  + (size_t)bc * HW;
    float*        ob = out + (size_t)bc * HW;

    int g0 = wv * 32;

    // ---- preload K fragments (16B row gathers, once per block) ----
    half8v ka[2][8];
    {
        const ushort* kr0 = kb + (g0 + l15) * 256 + l4 * 8;
        const ushort* kr1 = kb + (g0 + 16 + l15) * 256 + l4 * 8;
        #pragma unroll
        for (int kc = 0; kc < 8; ++kc) {
            ka[0][kc] = *(const half8v*)(kr0 + kc * 32);
            ka[1][kc] = *(const half8v*)(kr1 + kc * 32);
        }
    }

    // ---- preload V^T fragments via LDS transpose (fully unrolled) ----
    half8v va[2][8];
    {
        ushort* vstage = (ushort*)sbuf;     // [64][VSTR] = 34.3 KB
        #pragma unroll
        for (int hc = 0; hc < 4; ++hc) {
            #pragma unroll
            for (int s = 0; s < 4; ++s) {
                int id = t + s * 512;       // 64 rows x 32 segs
                int row = id >> 5, seg = id & 31;
                *(uint4*)&vstage[row * VSTR + seg * 8] =
                    *(const uint4*)(vb + (hc * 64 + row) * 256 + seg * 8);
            }
            LDS_BARRIER();
            #pragma unroll
            for (int gf = 0; gf < 2; ++gf)
                #pragma unroll
                for (int kcl = 0; kcl < 2; ++kcl) {
                    half8v v;
                    #pragma unroll
                    for (int j = 0; j < 8; ++j)
                        v[j] = *(const _Float16*)&vstage[(kcl * 32 + l4 * 8 + j) * VSTR
                                                         + g0 + gf * 16 + l15];
                    va[gf][hc * 2 + kcl] = v;
                }
            LDS_BARRIER();
        }
    }

    float w00 = wdw[c*9+0], w01 = wdw[c*9+1], w02 = wdw[c*9+2];
    float w10 = wdw[c*9+3], w11 = wdw[c*9+4], w12 = wdw[c*9+5];
    float w20 = wdw[c*9+6], w21 = wdw[c*9+7], w22 = wdw[c*9+8];
    float bias = bdw[c];

    half8v ones;
    #pragma unroll
    for (int j = 0; j < 8; ++j) ones[j] = (_Float16)1.0f;

    // ---- Q-stage addressing (per-thread constants) + tile-0 prologue ----
    int srow[3], scch[3];
    #pragma unroll
    for (int s = 0; s < 3; ++s) {
        int id = t + s * 512;               // 0..1535: 48 rows x 32 segs
        srow[s] = id >> 5; scch[s] = id & 31;
    }
    uint4 sv0, sv1, sv2;
    {
        int hq0 = min(max(-1 + srow[0], 0), 255);
        int hq1 = min(max(-1 + srow[1], 0), 255);
        int hq2 = min(max(-1 + srow[2], 0), 255);
        sv0 = *(const uint4*)(qb + hq0 * 256 + scch[0] * 8);
        sv1 = *(const uint4*)(qb + hq1 * 256 + scch[1] * 8);
        sv2 = *(const uint4*)(qb + hq2 * 256 + scch[2] * 8);
        *(uint4*)((char*)qlds + srow[0] * 512 + ((scch[0] ^ (srow[0] & 7)) << 4)) = sv0;
        *(uint4*)((char*)qlds + srow[1] * 512 + ((scch[1] ^ (srow[1] & 7)) << 4)) = sv1;
        *(uint4*)((char*)qlds + srow[2] * 512 + ((scch[2] ^ (srow[2] & 7)) << 4)) = sv2;
    }

    #pragma unroll 1
    for (int tile = 0; tile < 8; ++tile) {
        int h0 = tile * 32;

        LDS_BARRIER();   // BAR_A: qlds(t) visible; prev out-pass sbuf reads done

        // ===== Phase 1: S = Q K^T (Q from swizzled LDS, K from regs) =======
        {
            f32x4 acc[3][2];
            #pragma unroll
            for (int i = 0; i < 3; ++i)
                #pragma unroll
                for (int j = 0; j < 2; ++j) acc[i][j] = (f32x4)0.f;

            #pragma unroll
            for (int kc = 0; kc < 8; ++kc) {
                int ch4 = kc * 4 + l4;
                half8v q0 = *(const half8v*)((char*)qlds + (l15)      * 512 + ((ch4 ^ ( l15       & 7)) << 4));
                half8v q1 = *(const half8v*)((char*)qlds + (16 + l15) * 512 + ((ch4 ^ ((16 + l15) & 7)) << 4));
                half8v q2 = *(const half8v*)((char*)qlds + (32 + l15) * 512 + ((ch4 ^ ((32 + l15) & 7)) << 4));
                __builtin_amdgcn_s_setprio(1);
                acc[0][0] = __builtin_amdgcn_mfma_f32_16x16x32_f16(q0, ka[0][kc], acc[0][0], 0, 0, 0);
                acc[0][1] = __builtin_amdgcn_mfma_f32_16x16x32_f16(q0, ka[1][kc], acc[0][1], 0, 0, 0);
                acc[1][0] = __builtin_amdgcn_mfma_f32_16x16x32_f16(q1, ka[0][kc], acc[1][0], 0, 0, 0);
                acc[1][1] = __builtin_amdgcn_mfma_f32_16x16x32_f16(q1, ka[1][kc], acc[1][1], 0, 0, 0);
                acc[2][0] = __builtin_amdgcn_mfma_f32_16x16x32_f16(q2, ka[0][kc], acc[2][0], 0, 0, 0);
                acc[2][1] = __builtin_amdgcn_mfma_f32_16x16x32_f16(q2, ka[1][kc], acc[2][1], 0, 0, 0);
                __builtin_amdgcn_s_setprio(0);
            }

            // ---- issue next tile's Q loads (hide HBM latency under S-store+conv)
            if (tile < 7) {
                int nh0 = h0 + 32;
                int hq0 = min(max(nh0 - 1 + srow[0], 0), 255);
                int hq1 = min(max(nh0 - 1 + srow[1], 0), 255);
                int hq2 = min(max(nh0 - 1 + srow[2], 0), 255);
                sv0 = *(const uint4*)(qb + hq0 * 256 + scch[0] * 8);
                sv1 = *(const uint4*)(qb + hq1 * 256 + scch[1] * 8);
                sv2 = *(const uint4*)(qb + hq2 * 256 + scch[2] * 8);
            }

            // ---- S store ----
            #pragma unroll
            for (int hf = 0; hf < 3; ++hf)
                #pragma unroll
                for (int gf = 0; gf < 2; ++gf)
                    #pragma unroll
                    for (int r = 0; r < 4; ++r) {
                        int cr = hf * 16 + l4 * 4 + r;
                        if (cr < 34)
                            sbuf[cr * SST + g0 + gf * 16 + l15] = acc[hf][gf][r];
                    }
        }
        LDS_BARRIER();   // BAR_B: S visible; all P1 qlds reads done

        // ---- stage next tile's Q into qlds (writes drain at BAR_C) ----
        if (tile < 7) {
            *(uint4*)((char*)qlds + srow[0] * 512 + ((scch[0] ^ (srow[0] & 7)) << 4)) = sv0;
            *(uint4*)((char*)qlds + srow[1] * 512 + ((scch[1] ^ (srow[1] & 7)) << 4)) = sv1;
            *(uint4*)((char*)qlds + srow[2] * 512 + ((scch[2] ^ (srow[2] & 7)) << 4)) = sv2;
        }

        // ===== Phase 2: conv3x3, 4 cols/thread (b128 + shfl boundaries) =====
        float y[4][4], rmax[4];
        {
            f32x4 m0v, m1v, m2v;
            float l0v, r0v, l1v, r1v, l2v, r2v;

            auto rdrow = [&](int k, f32x4 &mv, float &lv, float &rv) {
                int sr = rg * 4 + k;
                bool valid = !((h0 == 0 && sr == 0) || (h0 + sr > 256));
                f32x4 z = (f32x4)0.f;
                mv = valid ? *(const f32x4*)&sbuf[sr * SST + c0] : z;
                float le = __shfl_up(mv[3], 1);
                float re = __shfl_down(mv[0], 1);
                lv = (col4 == 0) ? 0.f : le;
                rv = (col4 == 63) ? 0.f : re;
            };

            rdrow(0, m0v, l0v, r0v);
            rdrow(1, m1v, l1v, r1v);
            #pragma unroll
            for (int k = 2; k < 6; ++k) {
                rdrow(k, m2v, l2v, r2v);
                int i = k - 2;
                #pragma unroll
                for (int j = 0; j < 4; ++j) {
                    float a0 = (j == 0) ? l0v : m0v[j-1];
                    float b0 = m0v[j];
                    float e0 = (j == 3) ? r0v : m0v[j+1];
                    float a1 = (j == 0) ? l1v : m1v[j-1];
                    float b1 = m1v[j];
                    float e1 = (j == 3) ? r1v : m1v[j+1];
                    float a2 = (j == 0) ? l2v : m2v[j-1];
                    float b2 = m2v[j];
                    float e2 = (j == 3) ? r2v : m2v[j+1];
                    y[i][j] = bias
                        + w00*a0 + w01*b0 + w02*e0
                        + w10*a1 + w11*b1 + w12*e1
                        + w20*a2 + w21*b2 + w22*e2;
                }
                m0v = m1v; l0v = l1v; r0v = r1v;
                m1v = m2v; l1v = l2v; r1v = r2v;
            }

            #pragma unroll
            for (int i = 0; i < 4; ++i) {
                float m = fmaxf(fmaxf(y[i][0], y[i][1]), fmaxf(y[i][2], y[i][3]));
                #pragma unroll
                for (int off = 32; off > 0; off >>= 1)
                    m = fmaxf(m, __shfl_xor(m, off));
                rmax[i] = m;
            }
        }
        LDS_BARRIER();   // BAR_C: conv reads done; qlds writes drained

        // ===== Phase 3: exp -> f16 attn (b64 stores) =====
        ushort* attnb = (ushort*)sbuf;
        #pragma unroll
        for (int i = 0; i < 4; ++i) {
            int R = rg * 4 + i;
            union { ushort u[4]; uint2 v; } pk;
            #pragma unroll
            for (int j = 0; j < 4; ++j)
                pk.u[j] = f16_bits(__expf(y[i][j] - rmax[i]));
            *(uint2*)&attnb[R * ATS + c0] = pk.v;
        }
        LDS_BARRIER();   // BAR_D: attn visible

        // ===== Phase 4: PV + ones-sum (attn from LDS, V from regs) =====
        f32x4 pacc[2][2], accs[2];
        #pragma unroll
        for (int i = 0; i < 2; ++i) {
            accs[i] = (f32x4)0.f;
            #pragma unroll
            for (int j = 0; j < 2; ++j) pacc[i][j] = (f32x4)0.f;
        }

        #pragma unroll
        for (int kc = 0; kc < 8; ++kc) {
            half8v af0 = *(const half8v*)&attnb[l15 * ATS + kc * 32 + l4 * 8];
            half8v af1 = *(const half8v*)&attnb[(16 + l15) * ATS + kc * 32 + l4 * 8];
            __builtin_amdgcn_s_setprio(1);
            pacc[0][0] = __builtin_amdgcn_mfma_f32_16x16x32_f16(af0, va[0][kc], pacc[0][0], 0, 0, 0);
            pacc[0][1] = __builtin_amdgcn_mfma_f32_16x16x32_f16(af0, va[1][kc], pacc[0][1], 0, 0, 0);
            accs[0]    = __builtin_amdgcn_mfma_f32_16x16x32_f16(af0, ones, accs[0], 0, 0, 0);
            pacc[1][0] = __builtin_amdgcn_mfma_f32_16x16x32_f16(af1, va[0][kc], pacc[1][0], 0, 0, 0);
            pacc[1][1] = __builtin_amdgcn_mfma_f32_16x16x32_f16(af1, va[1][kc], pacc[1][1], 0, 0, 0);
            accs[1]    = __builtin_amdgcn_mfma_f32_16x16x32_f16(af1, ones, accs[1], 0, 0, 0);
            __builtin_amdgcn_s_setprio(0);
        }
        LDS_BARRIER();   // BAR_E: attn reads done before og overlay

        // ===== repack normalized output into LDS =====
        float* og = sbuf;                  // [32][SOT]
        #pragma unroll
        for (int hf = 0; hf < 2; ++hf)
            #pragma unroll
            for (int r = 0; r < 4; ++r) {
                int row = hf * 16 + l4 * 4 + r;
                float inv = 1.0f / accs[hf][r];
                #pragma unroll
                for (int wf = 0; wf < 2; ++wf)
                    og[row * SOT + g0 + wf * 16 + l15] = pacc[hf][wf][r] * inv;
            }
        LDS_BARRIER();   // BAR_F: og visible

        // ===== coalesced out pass: +x residual, 16B stores =====
        #pragma unroll
        for (int s = 0; s < 4; ++s) {
            int id = t + s * 512;          // 0..2047
            int row = id >> 6, seg = id & 63;
            f32x4 v = *(const f32x4*)&og[row * SOT + seg * 4];
            f32x4 xr = *(const f32x4*)&xb[(h0 + row) * 256 + seg * 4];
            v += xr;
            *(f32x4*)&ob[(h0 + row) * 256 + seg * 4] = v;
        }
        // loop-top BAR_A guards og reads vs next S-store and publishes qlds(t+1)
    }
}

// ---------------------------------------------------------------------------
extern "C" void kernel_launch(void* const* d_in, const int* in_sizes, int n_in,
                              void* d_out, int out_size, void* d_ws, size_t ws_size,
                              hipStream_t stream)
{
    const float* x     = (const float*)d_in[0];
    const float* w_qkv = (const float*)d_in[1];
    const float* b_qkv = (const float*)d_in[2];
    const float* w_dw  = (const float*)d_in[3];
    const float* b_dw  = (const float*)d_in[4];

    ushort* qf = (ushort*)d_ws;                  // q plane
    ushort* kf = qf + (size_t)BCHW;              // k plane
    ushort* vf = kf + (size_t)BCHW;              // v plane
    float*  out = (float*)d_out;

    qkv_kernel  <<<B * HW / 256, 256, 0, stream>>>(x, w_qkv, b_qkv, qf);
    fused_kernel<<<B * C,        512, 0, stream>>>(qf, kf, vf, w_dw, b_dw, x, out);
}

// Round 26
// 95.771 us; speedup vs baseline: 1.0959x; 1.0157x over previous
//
#include <hip/hip_runtime.h>
#include <math.h>

#define B 4
#define C 64
#define H 256
#define W 256
#define HW (H*W)            // 65536
#define CHW (C*HW)          // 4194304
#define BCHW (B*CHW)        // 16777216

typedef _Float16 half8v __attribute__((ext_vector_type(8)));
typedef float f32x4 __attribute__((ext_vector_type(4)));

// ws layout: 3 ushort(f16) planes of BCHW each (100 MB): q, k, v

__device__ inline ushort f16_bits(float f) {
    _Float16 h = (_Float16)f;
    return *(ushort*)&h;
}

// raw barrier: drain LDS only; global loads/stores stay in flight
#define LDS_BARRIER() do { \
    asm volatile("s_waitcnt lgkmcnt(0)" ::: "memory"); \
    __builtin_amdgcn_s_barrier(); \
} while (0)

// ---------------------------------------------------------------------------
// K1: qkv 1x1 conv as f16 MFMA GEMM. 6 chunks x 32 oc. WAVE-PRIVATE repack:
// zero block barriers (same-wave DS ordering + lgkmcnt). launch_bounds(256,4)
// -> 64 VGPR, no spill. (unchanged from r23/r25)
// ---------------------------------------------------------------------------
#define QPAD 72   // wave tile row stride (ushorts); 144 B, 16B-aligned

__global__ __launch_bounds__(256, 4) void qkv_kernel(
    const float* __restrict__ x, const float* __restrict__ w,
    const float* __restrict__ bias, ushort* __restrict__ qkv)
{
    __shared__ ushort tile[4][32 * QPAD];  // 18.4 KB
    int t = threadIdx.x;
    int lane = t & 63, wv = t >> 6;
    int l15 = lane & 15, l4 = lane >> 4;
    int p0 = blockIdx.x * 256;
    int b = p0 >> 16;
    int ppx = p0 & (HW - 1);               // pixel offset WITHIN batch b
    int pxw = ppx + wv * 64;

    const float* xb = x + (size_t)b * CHW;
    ushort* wt = tile[wv];                 // wave-private repack tile

    half8v bfr[4][2];
    #pragma unroll
    for (int pf = 0; pf < 4; ++pf)
        #pragma unroll
        for (int kc = 0; kc < 2; ++kc) {
            int k0 = kc * 32 + l4 * 8;
            int px = pxw + pf * 16 + l15;
            half8v hv;
            #pragma unroll
            for (int j = 0; j < 8; ++j)
                hv[j] = (_Float16)xb[(size_t)(k0 + j) * HW + px];
            bfr[pf][kc] = hv;
        }

    auto load_afr = [&](int ocb, half8v afr[2][2]) {
        #pragma unroll
        for (int nf = 0; nf < 2; ++nf)
            #pragma unroll
            for (int kc = 0; kc < 2; ++kc) {
                int oc = ocb + nf * 16 + l15;
                int k0 = kc * 32 + l4 * 8;
                const float4* wp = (const float4*)&w[oc * 64 + k0];
                float4 wa = wp[0], wb2 = wp[1];
                half8v a;
                a[0] = (_Float16)wa.x;  a[1] = (_Float16)wa.y;
                a[2] = (_Float16)wa.z;  a[3] = (_Float16)wa.w;
                a[4] = (_Float16)wb2.x; a[5] = (_Float16)wb2.y;
                a[6] = (_Float16)wb2.z; a[7] = (_Float16)wb2.w;
                afr[nf][kc] = a;
            }
    };

    half8v afrA[2][2], afrB[2][2];
    load_afr(0, afrA);

    #pragma unroll
    for (int ch = 0; ch < 6; ++ch) {
        int ocb = ch * 32;
        half8v (*cur)[2] = (ch & 1) ? afrB : afrA;
        half8v (*nxt)[2] = (ch & 1) ? afrA : afrB;

        f32x4 acc[2][4];
        #pragma unroll
        for (int nf = 0; nf < 2; ++nf)
            #pragma unroll
            for (int pf = 0; pf < 4; ++pf) acc[nf][pf] = (f32x4)0.f;

        #pragma unroll
        for (int kc = 0; kc < 2; ++kc)
            #pragma unroll
            for (int nf = 0; nf < 2; ++nf)
                #pragma unroll
                for (int pf = 0; pf < 4; ++pf)
                    acc[nf][pf] = __builtin_amdgcn_mfma_f32_16x16x32_f16(
                        cur[nf][kc], bfr[pf][kc], acc[nf][pf], 0, 0, 0);

        if (ch < 5) load_afr(ocb + 32, nxt);

        #pragma unroll
        for (int nf = 0; nf < 2; ++nf)
            #pragma unroll
            for (int r = 0; r < 4; ++r) {
                int ocl = nf * 16 + l4 * 4 + r;
                float bv = bias[ocb + ocl];
                #pragma unroll
                for (int pf = 0; pf < 4; ++pf)
                    wt[ocl * QPAD + pf * 16 + l15] =
                        f16_bits(acc[nf][pf][r] + bv);
            }

        asm volatile("s_waitcnt lgkmcnt(0)" ::: "memory");

        #pragma unroll
        for (int p = 0; p < 4; ++p) {
            int row = p * 8 + (lane >> 3);
            int c8  = lane & 7;
            uint4 val = *(const uint4*)&wt[row * QPAD + c8 * 8];
            int oc = ocb + row;
            ushort* dst = qkv + (size_t)(oc >> 6) * BCHW
                        + ((size_t)b * 64 + (oc & 63)) * HW + pxw + c8 * 8;
            *(uint4*)dst = val;
        }
    }
}

// ---------------------------------------------------------------------------
// K2 (fused, persistent per-bc, grid 256, 512 thr): r23 pipeline with
// (a) SEPARATE attn buffer (no sbuf overlay) -> 4 LDS-only barriers/tile
// (b) SOT 264->268 (og-repack stores 4-way -> 2-way bank aliasing)
// ---------------------------------------------------------------------------
#define SST 268                   // sbuf stride for S rows (f32); 268*4%16==0
#define ATS 264                   // attn row stride (f16); 528B, 16B-aligned
#define SOT 268                   // out-repack stride (f32); words%32==12
#define VSTR 268                  // V staging stride (f16)

__global__ __launch_bounds__(512, 2) void fused_kernel(
    const ushort* __restrict__ qf, const ushort* __restrict__ kf,
    const ushort* __restrict__ vf,
    const float* __restrict__ wdw, const float* __restrict__ bdw,
    const float* __restrict__ x, float* __restrict__ out)
{
    __shared__ float sbuf[34 * SST];        // 36.4 KB (V-stage / S / og)
    __shared__ ushort attnbuf[32 * ATS];    // 16.9 KB (attn, no overlay)
    __shared__ ushort qlds[48 * 256];       // 24 KB, XOR-swizzled Q tile

    int t = threadIdx.x;
    int lane = t & 63, wv = t >> 6;         // 8 waves
    int l15 = lane & 15, l4 = lane >> 4;
    int col4 = t & 63, rg = t >> 6;         // conv layout: 64 col-groups x 8 row-groups
    int c0 = col4 * 4;

    int bc = blockIdx.x;                    // one block per (b,c)
    int c = bc & 63;

    const ushort* qb = qf + (size_t)bc * HW;
    const ushort* kb = kf + (size_t)bc * HW;
    const ushort* vb = vf + (size_t)bc * HW;
    const float*  xb = x  + (size_t)bc * HW;
    float*        ob = out + (size_t)bc * HW;

    int g0 = wv * 32;

    // ---- preload K fragments (16B row gathers, once per block) ----
    half8v ka[2][8];
    {
        const ushort* kr0 = kb + (g0 + l15) * 256 + l4 * 8;
        const ushort* kr1 = kb + (g0 + 16 + l15) * 256 + l4 * 8;
        #pragma unroll
        for (int kc = 0; kc < 8; ++kc) {
            ka[0][kc] = *(const half8v*)(kr0 + kc * 32);
            ka[1][kc] = *(const half8v*)(kr1 + kc * 32);
        }
    }

    // ---- preload V^T fragments via LDS transpose (fully unrolled) ----
    half8v va[2][8];
    {
        ushort* vstage = (ushort*)sbuf;     // [64][VSTR] = 34.3 KB
        #pragma unroll
        for (int hc = 0; hc < 4; ++hc) {
            #pragma unroll
            for (int s = 0; s < 4; ++s) {
                int id = t + s * 512;       // 64 rows x 32 segs
                int row = id >> 5, seg = id & 31;
                *(uint4*)&vstage[row * VSTR + seg * 8] =
                    *(const uint4*)(vb + (hc * 64 + row) * 256 + seg * 8);
            }
            LDS_BARRIER();
            #pragma unroll
            for (int gf = 0; gf < 2; ++gf)
                #pragma unroll
                for (int kcl = 0; kcl < 2; ++kcl) {
                    half8v v;
                    #pragma unroll
                    for (int j = 0; j < 8; ++j)
                        v[j] = *(const _Float16*)&vstage[(kcl * 32 + l4 * 8 + j) * VSTR
                                                         + g0 + gf * 16 + l15];
                    va[gf][hc * 2 + kcl] = v;
                }
            LDS_BARRIER();
        }
    }

    float w00 = wdw[c*9+0], w01 = wdw[c*9+1], w02 = wdw[c*9+2];
    float w10 = wdw[c*9+3], w11 = wdw[c*9+4], w12 = wdw[c*9+5];
    float w20 = wdw[c*9+6], w21 = wdw[c*9+7], w22 = wdw[c*9+8];
    float bias = bdw[c];

    half8v ones;
    #pragma unroll
    for (int j = 0; j < 8; ++j) ones[j] = (_Float16)1.0f;

    // ---- Q-stage addressing (per-thread constants) + tile-0 prologue ----
    int srow[3], scch[3];
    #pragma unroll
    for (int s = 0; s < 3; ++s) {
        int id = t + s * 512;               // 0..1535: 48 rows x 32 segs
        srow[s] = id >> 5; scch[s] = id & 31;
    }
    uint4 sv0, sv1, sv2;
    {
        int hq0 = min(max(-1 + srow[0], 0), 255);
        int hq1 = min(max(-1 + srow[1], 0), 255);
        int hq2 = min(max(-1 + srow[2], 0), 255);
        sv0 = *(const uint4*)(qb + hq0 * 256 + scch[0] * 8);
        sv1 = *(const uint4*)(qb + hq1 * 256 + scch[1] * 8);
        sv2 = *(const uint4*)(qb + hq2 * 256 + scch[2] * 8);
        *(uint4*)((char*)qlds + srow[0] * 512 + ((scch[0] ^ (srow[0] & 7)) << 4)) = sv0;
        *(uint4*)((char*)qlds + srow[1] * 512 + ((scch[1] ^ (srow[1] & 7)) << 4)) = sv1;
        *(uint4*)((char*)qlds + srow[2] * 512 + ((scch[2] ^ (srow[2] & 7)) << 4)) = sv2;
    }

    #pragma unroll 1
    for (int tile = 0; tile < 8; ++tile) {
        int h0 = tile * 32;

        LDS_BARRIER();   // BAR_A: qlds(t) visible (drained at prev BAR_D);
                         //         prev out-pass og reads done -> S-store safe

        // ===== Phase 1: S = Q K^T (Q from swizzled LDS, K from regs) =======
        {
            f32x4 acc[3][2];
            #pragma unroll
            for (int i = 0; i < 3; ++i)
                #pragma unroll
                for (int j = 0; j < 2; ++j) acc[i][j] = (f32x4)0.f;

            #pragma unroll
            for (int kc = 0; kc < 8; ++kc) {
                int ch4 = kc * 4 + l4;
                half8v q0 = *(const half8v*)((char*)qlds + (l15)      * 512 + ((ch4 ^ ( l15       & 7)) << 4));
                half8v q1 = *(const half8v*)((char*)qlds + (16 + l15) * 512 + ((ch4 ^ ((16 + l15) & 7)) << 4));
                half8v q2 = *(const half8v*)((char*)qlds + (32 + l15) * 512 + ((ch4 ^ ((32 + l15) & 7)) << 4));
                __builtin_amdgcn_s_setprio(1);
                acc[0][0] = __builtin_amdgcn_mfma_f32_16x16x32_f16(q0, ka[0][kc], acc[0][0], 0, 0, 0);
                acc[0][1] = __builtin_amdgcn_mfma_f32_16x16x32_f16(q0, ka[1][kc], acc[0][1], 0, 0, 0);
                acc[1][0] = __builtin_amdgcn_mfma_f32_16x16x32_f16(q1, ka[0][kc], acc[1][0], 0, 0, 0);
                acc[1][1] = __builtin_amdgcn_mfma_f32_16x16x32_f16(q1, ka[1][kc], acc[1][1], 0, 0, 0);
                acc[2][0] = __builtin_amdgcn_mfma_f32_16x16x32_f16(q2, ka[0][kc], acc[2][0], 0, 0, 0);
                acc[2][1] = __builtin_amdgcn_mfma_f32_16x16x32_f16(q2, ka[1][kc], acc[2][1], 0, 0, 0);
                __builtin_amdgcn_s_setprio(0);
            }

            // ---- issue next tile's Q loads (hide HBM latency under S-store+conv)
            if (tile < 7) {
                int nh0 = h0 + 32;
                int hq0 = min(max(nh0 - 1 + srow[0], 0), 255);
                int hq1 = min(max(nh0 - 1 + srow[1], 0), 255);
                int hq2 = min(max(nh0 - 1 + srow[2], 0), 255);
                sv0 = *(const uint4*)(qb + hq0 * 256 + scch[0] * 8);
                sv1 = *(const uint4*)(qb + hq1 * 256 + scch[1] * 8);
                sv2 = *(const uint4*)(qb + hq2 * 256 + scch[2] * 8);
            }

            // ---- S store ----
            #pragma unroll
            for (int hf = 0; hf < 3; ++hf)
                #pragma unroll
                for (int gf = 0; gf < 2; ++gf)
                    #pragma unroll
                    for (int r = 0; r < 4; ++r) {
                        int cr = hf * 16 + l4 * 4 + r;
                        if (cr < 34)
                            sbuf[cr * SST + g0 + gf * 16 + l15] = acc[hf][gf][r];
                    }
        }
        LDS_BARRIER();   // BAR_B: S visible; all P1 qlds reads done

        // ---- stage next tile's Q into qlds (writes drain at BAR_D) ----
        if (tile < 7) {
            *(uint4*)((char*)qlds + srow[0] * 512 + ((scch[0] ^ (srow[0] & 7)) << 4)) = sv0;
            *(uint4*)((char*)qlds + srow[1] * 512 + ((scch[1] ^ (srow[1] & 7)) << 4)) = sv1;
            *(uint4*)((char*)qlds + srow[2] * 512 + ((scch[2] ^ (srow[2] & 7)) << 4)) = sv2;
        }

        // ===== Phase 2: conv3x3, 4 cols/thread (b128 + shfl boundaries) =====
        float y[4][4], rmax[4];
        {
            f32x4 m0v, m1v, m2v;
            float l0v, r0v, l1v, r1v, l2v, r2v;

            auto rdrow = [&](int k, f32x4 &mv, float &lv, float &rv) {
                int sr = rg * 4 + k;
                bool valid = !((h0 == 0 && sr == 0) || (h0 + sr > 256));
                f32x4 z = (f32x4)0.f;
                mv = valid ? *(const f32x4*)&sbuf[sr * SST + c0] : z;
                float le = __shfl_up(mv[3], 1);
                float re = __shfl_down(mv[0], 1);
                lv = (col4 == 0) ? 0.f : le;
                rv = (col4 == 63) ? 0.f : re;
            };

            rdrow(0, m0v, l0v, r0v);
            rdrow(1, m1v, l1v, r1v);
            #pragma unroll
            for (int k = 2; k < 6; ++k) {
                rdrow(k, m2v, l2v, r2v);
                int i = k - 2;
                #pragma unroll
                for (int j = 0; j < 4; ++j) {
                    float a0 = (j == 0) ? l0v : m0v[j-1];
                    float b0 = m0v[j];
                    float e0 = (j == 3) ? r0v : m0v[j+1];
                    float a1 = (j == 0) ? l1v : m1v[j-1];
                    float b1 = m1v[j];
                    float e1 = (j == 3) ? r1v : m1v[j+1];
                    float a2 = (j == 0) ? l2v : m2v[j-1];
                    float b2 = m2v[j];
                    float e2 = (j == 3) ? r2v : m2v[j+1];
                    y[i][j] = bias
                        + w00*a0 + w01*b0 + w02*e0
                        + w10*a1 + w11*b1 + w12*e1
                        + w20*a2 + w21*b2 + w22*e2;
                }
                m0v = m1v; l0v = l1v; r0v = r1v;
                m1v = m2v; l1v = l2v; r1v = r2v;
            }

            #pragma unroll
            for (int i = 0; i < 4; ++i) {
                float m = fmaxf(fmaxf(y[i][0], y[i][1]), fmaxf(y[i][2], y[i][3]));
                #pragma unroll
                for (int off = 32; off > 0; off >>= 1)
                    m = fmaxf(m, __shfl_xor(m, off));
                rmax[i] = m;
            }
        }

        // ===== Phase 3: exp -> f16 attn (separate buffer: no barrier needed;
        //        prev tile's P4 attnbuf reads completed before prev BAR_F) ====
        #pragma unroll
        for (int i = 0; i < 4; ++i) {
            int R = rg * 4 + i;
            union { ushort u[4]; uint2 v; } pk;
            #pragma unroll
            for (int j = 0; j < 4; ++j)
                pk.u[j] = f16_bits(__expf(y[i][j] - rmax[i]));
            *(uint2*)&attnbuf[R * ATS + c0] = pk.v;
        }
        LDS_BARRIER();   // BAR_D: attn visible; conv sbuf reads done (conv
                         //         precedes exp per wave); qlds writes drained

        // ===== Phase 4: PV + ones-sum (attn from LDS, V from regs) =====
        f32x4 pacc[2][2], accs[2];
        #pragma unroll
        for (int i = 0; i < 2; ++i) {
            accs[i] = (f32x4)0.f;
            #pragma unroll
            for (int j = 0; j < 2; ++j) pacc[i][j] = (f32x4)0.f;
        }

        #pragma unroll
        for (int kc = 0; kc < 8; ++kc) {
            half8v af0 = *(const half8v*)&attnbuf[l15 * ATS + kc * 32 + l4 * 8];
            half8v af1 = *(const half8v*)&attnbuf[(16 + l15) * ATS + kc * 32 + l4 * 8];
            __builtin_amdgcn_s_setprio(1);
            pacc[0][0] = __builtin_amdgcn_mfma_f32_16x16x32_f16(af0, va[0][kc], pacc[0][0], 0, 0, 0);
            pacc[0][1] = __builtin_amdgcn_mfma_f32_16x16x32_f16(af0, va[1][kc], pacc[0][1], 0, 0, 0);
            accs[0]    = __builtin_amdgcn_mfma_f32_16x16x32_f16(af0, ones, accs[0], 0, 0, 0);
            pacc[1][0] = __builtin_amdgcn_mfma_f32_16x16x32_f16(af1, va[0][kc], pacc[1][0], 0, 0, 0);
            pacc[1][1] = __builtin_amdgcn_mfma_f32_16x16x32_f16(af1, va[1][kc], pacc[1][1], 0, 0, 0);
            accs[1]    = __builtin_amdgcn_mfma_f32_16x16x32_f16(af1, ones, accs[1], 0, 0, 0);
            __builtin_amdgcn_s_setprio(0);
        }

        // ===== repack normalized output into sbuf (conv reads done @BAR_D;
        //        attnbuf disjoint -> no barrier needed) =====
        float* og = sbuf;                  // [32][SOT]
        #pragma unroll
        for (int hf = 0; hf < 2; ++hf)
            #pragma unroll
            for (int r = 0; r < 4; ++r) {
                int row = hf * 16 + l4 * 4 + r;
                float inv = 1.0f / accs[hf][r];
                #pragma unroll
                for (int wf = 0; wf < 2; ++wf)
                    og[row * SOT + g0 + wf * 16 + l15] = pacc[hf][wf][r] * inv;
            }
        LDS_BARRIER();   // BAR_F: og visible

        // ===== coalesced out pass: +x residual, 16B stores =====
        #pragma unroll
        for (int s = 0; s < 4; ++s) {
            int id = t + s * 512;          // 0..2047
            int row = id >> 6, seg = id & 63;
            f32x4 v = *(const f32x4*)&og[row * SOT + seg * 4];
            f32x4 xr = *(const f32x4*)&xb[(h0 + row) * 256 + seg * 4];
            v += xr;
            *(f32x4*)&ob[(h0 + row) * 256 + seg * 4] = v;
        }
        // loop-top BAR_A guards og reads vs next S-store and publishes qlds(t+1)
    }
}

// ---------------------------------------------------------------------------
extern "C" void kernel_launch(void* const* d_in, const int* in_sizes, int n_in,
                              void* d_out, int out_size, void* d_ws, size_t ws_size,
                              hipStream_t stream)
{
    const float* x     = (const float*)d_in[0];
    const float* w_qkv = (const float*)d_in[1];
    const float* b_qkv = (const float*)d_in[2];
    const float* w_dw  = (const float*)d_in[3];
    const float* b_dw  = (const float*)d_in[4];

    ushort* qf = (ushort*)d_ws;                  // q plane
    ushort* kf = qf + (size_t)BCHW;              // k plane
    ushort* vf = kf + (size_t)BCHW;              // v plane
    float*  out = (float*)d_out;

    qkv_kernel  <<<B * HW / 256, 256, 0, stream>>>(x, w_qkv, b_qkv, qf);
    fused_kernel<<<B * C,        512, 0, stream>>>(qf, kf, vf, w_dw, b_dw, x, out);
}